// Round 11
// baseline (220.632 us; speedup 1.0000x reference)
//
#include <hip/hip_runtime.h>

#define N_NODES_C 100000
#define N_EDGES_C 1600000
#define NPB 128                   // partition blocks
#define CH (N_EDGES_C / NPB)      // 12500 edges/partition block (exact)
#define BUCK_SH 7
#define BUCK_NODES 128
#define NB_BUCK 782               // ceil(100000 / 128)

typedef short short8 __attribute__((ext_vector_type(8)));
typedef float f32x4 __attribute__((ext_vector_type(4)));

// float -> bf16 bits (RNE)
__device__ __forceinline__ short f2bf(float f) {
  unsigned u = __builtin_bit_cast(unsigned, f);
  unsigned r = (u + 0x7FFFu + ((u >> 16) & 1u)) >> 16;
  return (short)r;
}
__device__ __forceinline__ float bf_lo(unsigned u) {
  return __builtin_bit_cast(float, u << 16);
}
__device__ __forceinline__ float bf_hi(unsigned u) {
  return __builtin_bit_cast(float, u & 0xFFFF0000u);
}

// ---------------------------------------------------------------------------
// MFMA GEMM body: out[n][64] = in[n][K] @ W[K][64] (layer 1 only)
// ---------------------------------------------------------------------------
template <int K, bool IN_BF, bool OUT_BF>
__device__ __forceinline__ void gemm64_body(
    int gblock, const void* __restrict__ in_, const float* __restrict__ W,
    void* __restrict__ out_, int n_rows) {
  constexpr int KS = K / 32;
  int wave = threadIdx.x >> 6;
  int lane = threadIdx.x & 63;
  int row0 = (gblock * 4 + wave) * 16;
  if (row0 >= n_rows) return;

  int lrow = lane & 15;
  int lk = (lane >> 4) * 8;

  short8 bfrag[KS][4];
#pragma unroll
  for (int ks = 0; ks < KS; ++ks)
#pragma unroll
    for (int nt = 0; nt < 4; ++nt) {
      short8 b;
#pragma unroll
      for (int j = 0; j < 8; ++j)
        b[j] = f2bf(W[(size_t)(ks * 32 + lk + j) * 64 + nt * 16 + lrow]);
      bfrag[ks][nt] = b;
    }

  int row = row0 + lrow;
  f32x4 acc[4] = {};
#pragma unroll
  for (int ks = 0; ks < KS; ++ks) {
    short8 a;
    if constexpr (IN_BF) {
      const short* ip = (const short*)in_ + (size_t)row * K + ks * 32 + lk;
      a = *(const short8*)ip;
    } else {
      const float* ip = (const float*)in_ + (size_t)row * K + ks * 32 + lk;
      f32x4 v0 = *(const f32x4*)(ip);
      f32x4 v1 = *(const f32x4*)(ip + 4);
#pragma unroll
      for (int j = 0; j < 4; ++j) {
        a[j] = f2bf(v0[j]);
        a[4 + j] = f2bf(v1[j]);
      }
    }
#pragma unroll
    for (int nt = 0; nt < 4; ++nt)
      acc[nt] = __builtin_amdgcn_mfma_f32_16x16x32_bf16(a, bfrag[ks][nt],
                                                        acc[nt], 0, 0, 0);
  }

  int crow = row0 + (lane >> 4) * 4;
#pragma unroll
  for (int nt = 0; nt < 4; ++nt) {
    int ocol = nt * 16 + lrow;
#pragma unroll
    for (int r = 0; r < 4; ++r) {
      if constexpr (OUT_BF)
        ((short*)out_)[(size_t)(crow + r) * 64 + ocol] = f2bf(acc[nt][r]);
      else
        ((float*)out_)[(size_t)(crow + r) * 64 + ocol] = acc[nt][r];
    }
  }
}

// ---------------------------------------------------------------------------
// Bucket histogram (LDS int atomics) -> countsT[bucket][blk], blk in [0,NPB)
// ---------------------------------------------------------------------------
__global__ __launch_bounds__(256) void hist_kernel(
    const int* __restrict__ dst, int* __restrict__ countsT) {
  __shared__ int lhist[NB_BUCK];
  int cb = (int)blockIdx.x;
  for (int i = threadIdx.x; i < NB_BUCK; i += 256) lhist[i] = 0;
  __syncthreads();
  int beg = cb * CH, end = beg + CH;
  for (int i = beg + (int)threadIdx.x; i < end; i += 256)
    atomicAdd(&lhist[((unsigned)dst[i]) >> BUCK_SH], 1);
  __syncthreads();
  for (int bb = threadIdx.x; bb < NB_BUCK; bb += 256)
    countsT[bb * NPB + cb] = lhist[bb];
}

// K1: per-bucket exclusive scan over NPB=128 per-block counts (+ total).
// One wave per bucket; lane holds 2 values.
__global__ __launch_bounds__(256) void scan_buckets_kernel(
    int* __restrict__ countsT, int* __restrict__ btot) {
  int b = blockIdx.x * 4 + (threadIdx.x >> 6);
  int lane = threadIdx.x & 63;
  if (b >= NB_BUCK) return;
  int2 v = *(const int2*)(countsT + b * NPB + lane * 2);
  int s = v.x + v.y;
  int incl = s;
#pragma unroll
  for (int d = 1; d < 64; d <<= 1) {
    int t = __shfl_up(incl, d, 64);
    if (lane >= d) incl += t;
  }
  int excl = incl - s;
  int2 o;
  o.x = excl;
  o.y = excl + v.x;
  *(int2*)(countsT + b * NPB + lane * 2) = o;
  if (lane == 63) btot[b] = incl;
}

// K2: exclusive scan of bucket totals -> bstart[0..NB_BUCK].
__global__ __launch_bounds__(1024) void scan_btot_kernel(
    const int* __restrict__ btot, int* __restrict__ bstart) {
  __shared__ int lds[1024];
  int t = threadIdx.x;
  int v = (t < NB_BUCK) ? btot[t] : 0;
  lds[t] = v;
  __syncthreads();
  for (int off = 1; off < 1024; off <<= 1) {
    int tv = (t >= off) ? lds[t - off] : 0;
    __syncthreads();
    lds[t] += tv;
    __syncthreads();
  }
  if (t < NB_BUCK) bstart[t] = lds[t] - v;
  if (t == NB_BUCK - 1) bstart[NB_BUCK] = lds[t];
}

// ---------------------------------------------------------------------------
// Partition (standalone): scatter packed edge words ((ldst<<17)|src) into
// bucket order. Runs are 16 edges = 64B (one line) -> L2-coalesced writes.
// ---------------------------------------------------------------------------
__global__ __launch_bounds__(256) void partition_kernel(
    const int* __restrict__ src, const int* __restrict__ dst,
    const int* __restrict__ offs /* countsT after K1 */,
    const int* __restrict__ bstart, unsigned* __restrict__ packed) {
  __shared__ int cur[NB_BUCK];
  int b = (int)blockIdx.x;
  for (int bb = threadIdx.x; bb < NB_BUCK; bb += 256)
    cur[bb] = bstart[bb] + offs[bb * NPB + b];
  __syncthreads();
  int beg = b * CH, end = beg + CH;
  for (int i = beg + (int)threadIdx.x; i < end; i += 256) {
    int d = dst[i];
    int s = src[i];
    int bb = ((unsigned)d) >> BUCK_SH;
    int pos = atomicAdd(&cur[bb], 1);
    packed[pos] = ((unsigned)(d & (BUCK_NODES - 1)) << 17) | (unsigned)s;
  }
}

// ---------------------------------------------------------------------------
// Fused: blocks [0, NB_BUCK) = per-bucket counting sort -> col/row_ptr;
// blocks [NB_BUCK, +gemm_grid) = GEMM1 (x@W1 -> hA bf16). Both streaming.
// ---------------------------------------------------------------------------
__global__ __launch_bounds__(256) void sort_gemm1_kernel(
    const unsigned* __restrict__ packed, const int* __restrict__ bstart,
    int* __restrict__ col, int* __restrict__ row_ptr, int n_nodes,
    int n_edges, const float* __restrict__ x, const float* __restrict__ W1,
    short* __restrict__ hA) {
  __shared__ int lhist[BUCK_NODES];
  __shared__ int lcur[BUCK_NODES];
  __shared__ int wsum0;
  int b = (int)blockIdx.x;
  if (b >= NB_BUCK) {
    gemm64_body<128, false, true>(b - NB_BUCK, x, W1, hA, n_nodes);
    return;
  }
  int beg = bstart[b], end = bstart[b + 1];
  int t = (int)threadIdx.x;

  if (t < BUCK_NODES) lhist[t] = 0;
  __syncthreads();
  for (int e = beg + t; e < end; e += 256)
    atomicAdd(&lhist[packed[e] >> 17], 1);
  __syncthreads();

  int v = 0, incl = 0;
  if (t < BUCK_NODES) {
    v = lhist[t];
    incl = v;
#pragma unroll
    for (int d = 1; d < 64; d <<= 1) {
      int u = __shfl_up(incl, d, 64);
      if ((t & 63) >= d) incl += u;
    }
  }
  if (t == 63) wsum0 = incl;
  __syncthreads();
  if (t >= 64 && t < BUCK_NODES) incl += wsum0;
  if (t < BUCK_NODES) {
    int excl = incl - v;
    lcur[t] = excl;
    int node = b * BUCK_NODES + t;
    if (node < n_nodes) row_ptr[node] = beg + excl;
  }
  if (b == NB_BUCK - 1 && t == 0) row_ptr[n_nodes] = n_edges;
  __syncthreads();

  for (int e = beg + t; e < end; e += 256) {
    unsigned pe = packed[e];
    int ld = (int)(pe >> 17);
    int pos = beg + atomicAdd(&lcur[ld], 1);
    col[pos] = (int)(pe & 0x1FFFFu);
  }
}

// ---------------------------------------------------------------------------
// Agg inner: aggregate one node's sorted edge range; returns s0..s3 for the
// channel quad q (all 64 lanes hold the result after the two shuffles).
// ---------------------------------------------------------------------------
__device__ __forceinline__ void agg_node(
    const short* __restrict__ h, const int* __restrict__ col, int beg, int end,
    int slot, int q, float& s0, float& s1, float& s2, float& s3) {
  s0 = s1 = s2 = s3 = 0.f;
  float t0 = 0.f, t1 = 0.f, t2 = 0.f, t3 = 0.f;
  int e = beg + slot;
  for (; e + 12 < end; e += 16) {
    int sa = col[e];
    int sb = col[e + 4];
    int sc = col[e + 8];
    int sd = col[e + 12];
    uint2 ua = *(const uint2*)(h + (size_t)sa * 64 + q * 4);
    uint2 ub = *(const uint2*)(h + (size_t)sb * 64 + q * 4);
    uint2 uc = *(const uint2*)(h + (size_t)sc * 64 + q * 4);
    uint2 ud = *(const uint2*)(h + (size_t)sd * 64 + q * 4);
    s0 += bf_lo(ua.x) + bf_lo(ub.x);
    s1 += bf_hi(ua.x) + bf_hi(ub.x);
    s2 += bf_lo(ua.y) + bf_lo(ub.y);
    s3 += bf_hi(ua.y) + bf_hi(ub.y);
    t0 += bf_lo(uc.x) + bf_lo(ud.x);
    t1 += bf_hi(uc.x) + bf_hi(ud.x);
    t2 += bf_lo(uc.y) + bf_lo(ud.y);
    t3 += bf_hi(uc.y) + bf_hi(ud.y);
  }
  for (; e < end; e += 4) {
    int sa = col[e];
    uint2 ua = *(const uint2*)(h + (size_t)sa * 64 + q * 4);
    s0 += bf_lo(ua.x);
    s1 += bf_hi(ua.x);
    s2 += bf_lo(ua.y);
    s3 += bf_hi(ua.y);
  }
  s0 += t0;
  s1 += t1;
  s2 += t2;
  s3 += t3;
  s0 += __shfl_xor(s0, 16);
  s1 += __shfl_xor(s1, 16);
  s2 += __shfl_xor(s2, 16);
  s3 += __shfl_xor(s3, 16);
  s0 += __shfl_xor(s0, 32);
  s1 += __shfl_xor(s1, 32);
  s2 += __shfl_xor(s2, 32);
  s3 += __shfl_xor(s3, 32);
}

// ---------------------------------------------------------------------------
// Fused agg + bias + ReLU + (row @ W) -> bf16. Block = 16 nodes, 4 waves.
// ---------------------------------------------------------------------------
__global__ __launch_bounds__(256) void agg_gemm_kernel(
    const short* __restrict__ h, const int* __restrict__ row_ptr,
    const int* __restrict__ col, const float* __restrict__ bias,
    const float* __restrict__ W, short* __restrict__ outg, int n_nodes) {
  __shared__ float rowbuf[16][68];
  int wid = threadIdx.x >> 6;
  int lane = threadIdx.x & 63;
  int slot = lane >> 4;
  int q = lane & 15;
  int nbase = blockIdx.x * 16;

#pragma unroll
  for (int n = 0; n < 4; ++n) {
    int ln = wid * 4 + n;
    int node = nbase + ln;
    float s0, s1, s2, s3;
    agg_node(h, col, row_ptr[node], row_ptr[node + 1], slot, q, s0, s1, s2, s3);
    if (lane < 16) {
      f32x4 r;
      r[0] = fmaxf(s0 + bias[q * 4 + 0], 0.f);
      r[1] = fmaxf(s1 + bias[q * 4 + 1], 0.f);
      r[2] = fmaxf(s2 + bias[q * 4 + 2], 0.f);
      r[3] = fmaxf(s3 + bias[q * 4 + 3], 0.f);
      *(f32x4*)&rowbuf[ln][q * 4] = r;
    }
  }
  __syncthreads();

  int lrow = lane & 15;
  int lk = (lane >> 4) * 8;
  f32x4 acc = {};
#pragma unroll
  for (int ks = 0; ks < 2; ++ks) {
    short8 a, bv;
#pragma unroll
    for (int j = 0; j < 8; ++j) a[j] = f2bf(rowbuf[lrow][ks * 32 + lk + j]);
#pragma unroll
    for (int j = 0; j < 8; ++j)
      bv[j] = f2bf(W[(size_t)(ks * 32 + lk + j) * 64 + wid * 16 + lrow]);
    acc = __builtin_amdgcn_mfma_f32_16x16x32_bf16(a, bv, acc, 0, 0, 0);
  }
  int crow = (lane >> 4) * 4;
#pragma unroll
  for (int r = 0; r < 4; ++r)
    outg[(size_t)(nbase + crow + r) * 64 + wid * 16 + lrow] = f2bf(acc[r]);
}

// ---------------------------------------------------------------------------
// Final agg + bias + ReLU (fp32 out). Wave per node.
// ---------------------------------------------------------------------------
__global__ __launch_bounds__(256) void agg_final_kernel(
    const short* __restrict__ h, const int* __restrict__ row_ptr,
    const int* __restrict__ col, const float* __restrict__ bias,
    float* __restrict__ out, int n_nodes) {
  int node = blockIdx.x * 4 + (threadIdx.x >> 6);
  if (node >= n_nodes) return;
  int lane = threadIdx.x & 63;
  int slot = lane >> 4;
  int q = lane & 15;
  float s0, s1, s2, s3;
  agg_node(h, col, row_ptr[node], row_ptr[node + 1], slot, q, s0, s1, s2, s3);
  if (lane < 16) {
    float4 v;
    v.x = fmaxf(s0 + bias[q * 4 + 0], 0.f);
    v.y = fmaxf(s1 + bias[q * 4 + 1], 0.f);
    v.z = fmaxf(s2 + bias[q * 4 + 2], 0.f);
    v.w = fmaxf(s3 + bias[q * 4 + 3], 0.f);
    ((float4*)out)[(size_t)node * 16 + q] = v;
  }
}

extern "C" void kernel_launch(void* const* d_in, const int* in_sizes, int n_in,
                              void* d_out, int out_size, void* d_ws,
                              size_t ws_size, hipStream_t stream) {
  const float* x = (const float*)d_in[0];
  const int* src = (const int*)d_in[1];
  const int* dst = (const int*)d_in[2];
  const float* W1 = (const float*)d_in[3];
  const float* b1 = (const float*)d_in[4];
  const float* W2 = (const float*)d_in[5];
  const float* b2 = (const float*)d_in[6];
  const float* W3 = (const float*)d_in[7];
  const float* b3 = (const float*)d_in[8];
  float* out = (float*)d_out;

  const int N = N_NODES_C;
  const int E = N_EDGES_C;

  // Workspace layout (43 MB):
  //   [0, 1MB)     countsT[NB_BUCK][NPB] (400 KB; becomes offs after K1)
  //   [1MB, +4KB)  btot ; [1MB+16KB) bstart
  //   [2, 3MB)     row_ptr (N+1)
  //   [3, 10MB)    packed edges (E u32)
  //   [10, 17MB)   col (E int, dst-sorted src)
  //   [17, 30MB)   hA ; [30, 43MB) hB
  char* ws = (char*)d_ws;
  int* countsT = (int*)(ws + 0);
  int* btot = (int*)(ws + (1u << 20));
  int* bstart = (int*)(ws + (1u << 20) + (16u << 10));
  int* row_ptr = (int*)(ws + (2u << 20));
  unsigned* packed = (unsigned*)(ws + (3u << 20));
  int* col = (int*)(ws + (10u << 20));
  short* hA = (short*)(ws + (17u << 20));
  short* hB = (short*)(ws + (30u << 20));

  const int gemm_grid = (N + 63) / 64;  // 1563
  const int k1_grid = (NB_BUCK + 3) / 4;
  const int aggg_grid = N / 16;         // 6250
  const int aggf_grid = (N + 3) / 4;    // 25000

  // ---- CSR build; gemm1 overlapped with the (streaming) sort ----
  hist_kernel<<<NPB, 256, 0, stream>>>(dst, countsT);
  scan_buckets_kernel<<<k1_grid, 256, 0, stream>>>(countsT, btot);
  scan_btot_kernel<<<1, 1024, 0, stream>>>(btot, bstart);
  partition_kernel<<<NPB, 256, 0, stream>>>(src, dst, countsT, bstart, packed);
  sort_gemm1_kernel<<<NB_BUCK + gemm_grid, 256, 0, stream>>>(
      packed, bstart, col, row_ptr, N, E, x, W1, hA);

  // ---- Layer 1 agg fused with gemm2: hB = relu(agg(hA)+b1) @ W2 ----
  agg_gemm_kernel<<<aggg_grid, 256, 0, stream>>>(hA, row_ptr, col, b1, W2, hB,
                                                 N);
  // ---- Layer 2 agg fused with gemm3: hA = relu(agg(hB)+b2) @ W3 ----
  agg_gemm_kernel<<<aggg_grid, 256, 0, stream>>>(hB, row_ptr, col, b2, W3, hA,
                                                 N);
  // ---- Layer 3 final: out = relu(agg(hA)+b3) (fp32) ----
  agg_final_kernel<<<aggf_grid, 256, 0, stream>>>(hA, row_ptr, col, b3, out, N);
}